// Round 2
// baseline (271.693 us; speedup 1.0000x reference)
//
#include <hip/hip_runtime.h>
#include <math.h>

// Problem constants (from setup_inputs): B=64, H=2048, NH=8, HD=256
constexpr int Bb  = 64;
constexpr int Hh  = 2048;
constexpr int NHh = 8;
constexpr int HDd = 256;

// Output flat offsets (c_new, n_new, m_new, h_norm), all f32
constexpr size_t C_OFF = 0;
constexpr size_t N_OFF = (size_t)Bb * NHh * HDd * HDd;            // 33554432
constexpr size_t M_OFF = N_OFF + (size_t)Bb * NHh * HDd;          // 33685504
constexpr size_t H_OFF = M_OFF + (size_t)Bb * NHh;                // 33686016

// ---------------------------------------------------------------------------
// Kernel A: per-batch gate computation.
// grid = B blocks, 256 threads. Each block computes i_tilde/f_tilde for all
// 8 heads with coalesced float4 loads of the weight ROWS (W is (3H, NH)
// row-major, so W[r*8 .. r*8+7] is contiguous).
// Emits per-(b,h): ws[(b*8+h)*4] = {f_prime, i_prime, m_new, unused}
// and writes the m_new output.
// ---------------------------------------------------------------------------
__global__ __launch_bounds__(256) void gates_kernel(
    const float* __restrict__ q, const float* __restrict__ k,
    const float* __restrict__ v, const float* __restrict__ m_in,
    const float* __restrict__ wi_k, const float* __restrict__ wi_b,
    const float* __restrict__ wf_k, const float* __restrict__ wf_b,
    float* __restrict__ ws, float* __restrict__ out_m)
{
    const int b    = blockIdx.x;
    const int t    = threadIdx.x;
    const int lane = t & 63;
    const int wv   = t >> 6;

    float ai[8], af[8];
#pragma unroll
    for (int i = 0; i < 8; ++i) { ai[i] = 0.f; af[i] = 0.f; }

#pragma unroll 4
    for (int j = 0; j < 24; ++j) {
        const int r = t + 256 * j;
        float x;
        if (r < Hh)            x = q[b * Hh + r];
        else if (r < 2 * Hh)   x = k[b * Hh + r - Hh];
        else                   x = v[b * Hh + r - 2 * Hh];

        const float4 wa = *(const float4*)(wi_k + (size_t)r * 8);
        const float4 wb = *(const float4*)(wi_k + (size_t)r * 8 + 4);
        ai[0] = fmaf(x, wa.x, ai[0]); ai[1] = fmaf(x, wa.y, ai[1]);
        ai[2] = fmaf(x, wa.z, ai[2]); ai[3] = fmaf(x, wa.w, ai[3]);
        ai[4] = fmaf(x, wb.x, ai[4]); ai[5] = fmaf(x, wb.y, ai[5]);
        ai[6] = fmaf(x, wb.z, ai[6]); ai[7] = fmaf(x, wb.w, ai[7]);

        const float4 fa = *(const float4*)(wf_k + (size_t)r * 8);
        const float4 fb = *(const float4*)(wf_k + (size_t)r * 8 + 4);
        af[0] = fmaf(x, fa.x, af[0]); af[1] = fmaf(x, fa.y, af[1]);
        af[2] = fmaf(x, fa.z, af[2]); af[3] = fmaf(x, fa.w, af[3]);
        af[4] = fmaf(x, fb.x, af[4]); af[5] = fmaf(x, fb.y, af[5]);
        af[6] = fmaf(x, fb.z, af[6]); af[7] = fmaf(x, fb.w, af[7]);
    }

    // wave-level reduce each of the 16 accumulators
#pragma unroll
    for (int i = 0; i < 8; ++i) {
#pragma unroll
        for (int o = 32; o > 0; o >>= 1) {
            ai[i] += __shfl_down(ai[i], o, 64);
            af[i] += __shfl_down(af[i], o, 64);
        }
    }

    __shared__ float s_part[4][16];
    if (lane == 0) {
#pragma unroll
        for (int i = 0; i < 8; ++i) {
            s_part[wv][i]     = ai[i];
            s_part[wv][8 + i] = af[i];
        }
    }
    __syncthreads();

    if (t < 8) {
        const int h = t;
        const float it = s_part[0][h] + s_part[1][h] + s_part[2][h] + s_part[3][h]
                         + wi_b[h];
        const float ft = s_part[0][8 + h] + s_part[1][8 + h] + s_part[2][8 + h]
                         + s_part[3][8 + h] + wf_b[h];
        // log sigmoid(ft) = -softplus(-ft), numerically stable
        const float logf_ = -(fmaxf(-ft, 0.f) + log1pf(expf(-fabsf(ft))));
        const float m_old = m_in[b * NHh + h];
        const float m_new = fmaxf(logf_ + m_old, it);
        const float ip    = expf(it - m_new);
        const float fp    = expf(logf_ + m_old - m_new);
        const int blk = b * NHh + h;
        ws[blk * 4 + 0] = fp;
        ws[blk * 4 + 1] = ip;
        ws[blk * 4 + 2] = m_new;
        out_m[blk] = m_new;
    }
}

// ---------------------------------------------------------------------------
// Kernel B: per-(b,h) cell update.
// grid = B*NH = 512 blocks, 256 threads.
// Thread layout over the 256x256 tile: wave wv owns rows {wv, wv+4, ...},
// lane owns float4-column `lane` (columns 4*lane .. 4*lane+3).
// Streams c -> c_new (coalesced dwordx4) while accumulating the qh^T @ c_new
// column sums in registers; then n_new, denominator, and LayerNorm.
// ---------------------------------------------------------------------------
__global__ __launch_bounds__(256) void cell_kernel(
    const float* __restrict__ q, const float* __restrict__ k,
    const float* __restrict__ v, const float* __restrict__ c_in,
    const float* __restrict__ n_in, const float* __restrict__ ln_s,
    const float* __restrict__ ws, float* __restrict__ out)
{
    const int blk  = blockIdx.x;   // b*8 + h
    const int b    = blk >> 3;
    const int h    = blk & 7;
    const int t    = threadIdx.x;
    const int lane = t & 63;
    const int wv   = t >> 6;

    __shared__ float  s_q[HDd];
    __shared__ float  s_k[HDd];    // kh (already /16)
    __shared__ float  s_v[HDd];
    __shared__ float4 s_nom[4][64];
    __shared__ float  s_dred[4];

    const float fp = ws[blk * 4 + 0];
    const float ip = ws[blk * 4 + 1];
    const float mn = ws[blk * 4 + 2];

    // head slices
    const float qv = q[b * Hh + h * HDd + t];
    const float kv = k[b * Hh + h * HDd + t] * 0.0625f;  // 1/sqrt(256)
    s_q[t] = qv;
    s_k[t] = kv;
    s_v[t] = v[b * Hh + h * HDd + t];

    // n_new and denominator partial (uses only this thread's own elements)
    const float nn = fmaf(fp, n_in[(size_t)blk * HDd + t], ip * kv);
    out[N_OFF + (size_t)blk * HDd + t] = nn;
    float pd = qv * nn;
#pragma unroll
    for (int o = 32; o > 0; o >>= 1) pd += __shfl_down(pd, o, 64);
    if (lane == 0) s_dred[wv] = pd;

    __syncthreads();   // s_q/s_k/s_v (and s_dred) now visible

    // main tile stream
    const size_t cbase = (size_t)blk * (HDd * HDd);
    const float4* cin  = (const float4*)(c_in + cbase);
    float4*       cout = (float4*)(out + C_OFF + cbase);
    const float4  vh4  = ((const float4*)s_v)[lane];
    float4 nom = make_float4(0.f, 0.f, 0.f, 0.f);

#pragma unroll 8
    for (int d1 = wv; d1 < HDd; d1 += 4) {
        const float a   = ip * s_k[d1];     // i' * kh[d1]  (wave-uniform, LDS bcast)
        const float qh1 = s_q[d1];
        const int   idx = d1 * 64 + lane;
        const float4 cv = cin[idx];
        float4 cn;
        cn.x = fmaf(fp, cv.x, a * vh4.x);
        cn.y = fmaf(fp, cv.y, a * vh4.y);
        cn.z = fmaf(fp, cv.z, a * vh4.z);
        cn.w = fmaf(fp, cv.w, a * vh4.w);
        cout[idx] = cn;
        nom.x = fmaf(qh1, cn.x, nom.x);
        nom.y = fmaf(qh1, cn.y, nom.y);
        nom.z = fmaf(qh1, cn.z, nom.z);
        nom.w = fmaf(qh1, cn.w, nom.w);
    }
    s_nom[wv][lane] = nom;
    __syncthreads();

    if (t < 64) {
        float4 n0 = s_nom[0][t], n1 = s_nom[1][t], n2 = s_nom[2][t], n3 = s_nom[3][t];
        float4 nt;
        nt.x = n0.x + n1.x + n2.x + n3.x;
        nt.y = n0.y + n1.y + n2.y + n3.y;
        nt.z = n0.z + n1.z + n2.z + n3.z;
        nt.w = n0.w + n1.w + n2.w + n3.w;

        const float dd    = s_dred[0] + s_dred[1] + s_dred[2] + s_dred[3];
        const float denom = fmaxf(fabsf(dd), expf(-mn)) + 1e-6f;

        float4 ht;
        ht.x = nt.x / denom; ht.y = nt.y / denom;
        ht.z = nt.z / denom; ht.w = nt.w / denom;

        // LayerNorm over the 256 h_tilde values (64 lanes x 4)
        float s = ht.x + ht.y + ht.z + ht.w;
#pragma unroll
        for (int o = 32; o > 0; o >>= 1) s += __shfl_down(s, o, 64);
        s = __shfl(s, 0, 64);
        const float mu = s * (1.f / 256.f);

        float vs = (ht.x - mu) * (ht.x - mu) + (ht.y - mu) * (ht.y - mu)
                 + (ht.z - mu) * (ht.z - mu) + (ht.w - mu) * (ht.w - mu);
#pragma unroll
        for (int o = 32; o > 0; o >>= 1) vs += __shfl_down(vs, o, 64);
        vs = __shfl(vs, 0, 64);
        const float rs = rsqrtf(vs * (1.f / 256.f) + 1e-6f);

        const float4 lns = ((const float4*)(ln_s + h * HDd))[t];
        float4 hn;
        hn.x = (ht.x - mu) * rs * lns.x;
        hn.y = (ht.y - mu) * rs * lns.y;
        hn.z = (ht.z - mu) * rs * lns.z;
        hn.w = (ht.w - mu) * rs * lns.w;
        ((float4*)(out + H_OFF + (size_t)b * Hh + h * HDd))[t] = hn;
    }
}

extern "C" void kernel_launch(void* const* d_in, const int* in_sizes, int n_in,
                              void* d_out, int out_size, void* d_ws, size_t ws_size,
                              hipStream_t stream)
{
    const float* q    = (const float*)d_in[0];
    const float* k    = (const float*)d_in[1];
    const float* v    = (const float*)d_in[2];
    const float* c    = (const float*)d_in[3];
    const float* n    = (const float*)d_in[4];
    const float* m    = (const float*)d_in[5];
    const float* wi_k = (const float*)d_in[6];
    const float* wi_b = (const float*)d_in[7];
    const float* wf_k = (const float*)d_in[8];
    const float* wf_b = (const float*)d_in[9];
    const float* ln_s = (const float*)d_in[10];
    float* out = (float*)d_out;
    float* ws  = (float*)d_ws;

    gates_kernel<<<dim3(Bb), dim3(256), 0, stream>>>(
        q, k, v, m, wi_k, wi_b, wf_k, wf_b, ws, out + M_OFF);
    cell_kernel<<<dim3(Bb * NHh), dim3(256), 0, stream>>>(
        q, k, v, c, n, ln_s, ws, out);
}

// Round 3
// 269.203 us; speedup vs baseline: 1.0092x; 1.0092x over previous
//
#include <hip/hip_runtime.h>
#include <math.h>

// Problem constants (from setup_inputs): B=64, H=2048, NH=8, HD=256
constexpr int Bb  = 64;
constexpr int Hh  = 2048;
constexpr int NHh = 8;
constexpr int HDd = 256;

// Output flat offsets (c_new, n_new, m_new, h_norm), all f32
constexpr size_t C_OFF = 0;
constexpr size_t N_OFF = (size_t)Bb * NHh * HDd * HDd;            // 33554432
constexpr size_t M_OFF = N_OFF + (size_t)Bb * NHh * HDd;          // 33685504
constexpr size_t H_OFF = M_OFF + (size_t)Bb * NHh;                // 33686016

// ---------------------------------------------------------------------------
// Fully fused mLSTM cell: one block per (b,h), 1024 threads (16 waves).
// __launch_bounds__(1024, 8): 8 waves/EU => 2 blocks/CU => 32 waves/CU (100%
// occupancy), VGPR capped at 64 (kernel needs ~40).
//
// Phase 1: gates. All 1024 threads do a 6-element slice of the 6144-long
//          dot qkv[b,:] . W[:,h] for both wi and wf (weights L2-resident:
//          all 512 blocks read the same 392 KB). Reduce via shfl + LDS.
// Phase 2: n_new + denominator partials (first 256 threads).
// Phase 3: stream the 256x256 c tile. Wave wv handles rows {16j + wv};
//          lane owns float4-column `lane` => every access is a coalesced
//          dwordx4. qh^T @ c_new accumulates in registers during the stream.
// Phase 4: cross-wave reduce + LayerNorm (wave 0).
// ---------------------------------------------------------------------------
__global__ __launch_bounds__(1024, 8) void fused_cell_kernel(
    const float* __restrict__ q, const float* __restrict__ k,
    const float* __restrict__ v, const float* __restrict__ c_in,
    const float* __restrict__ n_in, const float* __restrict__ m_in,
    const float* __restrict__ wi_k, const float* __restrict__ wi_b,
    const float* __restrict__ wf_k, const float* __restrict__ wf_b,
    const float* __restrict__ ln_s, float* __restrict__ out)
{
    const int blk  = blockIdx.x;   // b*8 + h
    const int b    = blk >> 3;
    const int h    = blk & 7;
    const int t    = threadIdx.x;
    const int lane = t & 63;
    const int wv   = t >> 6;       // 0..15

    __shared__ float  s_q[HDd];
    __shared__ float  s_k[HDd];    // kh (already /16)
    __shared__ float  s_v[HDd];
    __shared__ float4 s_nom[16][64];
    __shared__ float  s_red[16][2];
    __shared__ float  s_dred[4];
    __shared__ float  s_gate[3];   // fp, ip, m_new

    // ---- Phase 1: gate dot (all threads) + head-slice staging (t<256) ----
    float ai = 0.f, af = 0.f;
#pragma unroll
    for (int j = 0; j < 6; ++j) {
        const int r = t + 1024 * j;          // branch is uniform per j
        float x;
        if (r < Hh)            x = q[b * Hh + r];
        else if (r < 2 * Hh)   x = k[b * Hh + r - Hh];
        else                   x = v[b * Hh + r - 2 * Hh];
        ai = fmaf(x, wi_k[(size_t)r * 8 + h], ai);
        af = fmaf(x, wf_k[(size_t)r * 8 + h], af);
    }
#pragma unroll
    for (int o = 32; o > 0; o >>= 1) {
        ai += __shfl_down(ai, o, 64);
        af += __shfl_down(af, o, 64);
    }
    if (lane == 0) { s_red[wv][0] = ai; s_red[wv][1] = af; }

    if (t < HDd) {
        s_q[t] = q[b * Hh + h * HDd + t];
        s_k[t] = k[b * Hh + h * HDd + t] * 0.0625f;   // 1/sqrt(256)
        s_v[t] = v[b * Hh + h * HDd + t];
    }
    __syncthreads();

    if (t == 0) {
        float it = wi_b[h], ft = wf_b[h];
#pragma unroll
        for (int w = 0; w < 16; ++w) { it += s_red[w][0]; ft += s_red[w][1]; }
        // log sigmoid(ft) = -softplus(-ft), numerically stable
        const float logf_ = -(fmaxf(-ft, 0.f) + log1pf(expf(-fabsf(ft))));
        const float m_old = m_in[blk];
        const float m_new = fmaxf(logf_ + m_old, it);
        s_gate[0] = expf(logf_ + m_old - m_new);   // f'
        s_gate[1] = expf(it - m_new);              // i'
        s_gate[2] = m_new;
        out[M_OFF + blk] = m_new;
    }
    __syncthreads();

    const float fp = s_gate[0];
    const float ip = s_gate[1];
    const float mn = s_gate[2];

    // ---- Phase 2: n_new + denominator partials (first 4 waves) ----
    if (t < HDd) {
        const float nn = fmaf(fp, n_in[(size_t)blk * HDd + t], ip * s_k[t]);
        out[N_OFF + (size_t)blk * HDd + t] = nn;
        float pd = s_q[t] * nn;
#pragma unroll
        for (int o = 32; o > 0; o >>= 1) pd += __shfl_down(pd, o, 64);
        if (lane == 0) s_dred[wv] = pd;
    }
    // s_dred consumed only after the next __syncthreads (post main loop)

    // ---- Phase 3: stream the c tile ----
    const size_t cbase = (size_t)blk * (HDd * HDd);
    const float4* cin  = (const float4*)(c_in + cbase);
    float4*       cout = (float4*)(out + C_OFF + cbase);
    const float4  vh4  = ((const float4*)s_v)[lane];
    float4 nom = make_float4(0.f, 0.f, 0.f, 0.f);

#pragma unroll 4
    for (int j = 0; j < 16; ++j) {
        const int   d1  = 16 * j + wv;
        const float a   = ip * s_k[d1];     // wave-uniform LDS broadcast
        const float qh1 = s_q[d1];
        const int   idx = d1 * 64 + lane;
        const float4 cv = cin[idx];
        float4 cn;
        cn.x = fmaf(fp, cv.x, a * vh4.x);
        cn.y = fmaf(fp, cv.y, a * vh4.y);
        cn.z = fmaf(fp, cv.z, a * vh4.z);
        cn.w = fmaf(fp, cv.w, a * vh4.w);
        cout[idx] = cn;
        nom.x = fmaf(qh1, cn.x, nom.x);
        nom.y = fmaf(qh1, cn.y, nom.y);
        nom.z = fmaf(qh1, cn.z, nom.z);
        nom.w = fmaf(qh1, cn.w, nom.w);
    }
    s_nom[wv][lane] = nom;
    __syncthreads();

    // ---- Phase 4: reduce + LayerNorm (wave 0) ----
    if (t < 64) {
        float4 nt = make_float4(0.f, 0.f, 0.f, 0.f);
#pragma unroll
        for (int w = 0; w < 16; ++w) {
            const float4 p = s_nom[w][t];
            nt.x += p.x; nt.y += p.y; nt.z += p.z; nt.w += p.w;
        }

        const float dd    = s_dred[0] + s_dred[1] + s_dred[2] + s_dred[3];
        const float denom = fmaxf(fabsf(dd), expf(-mn)) + 1e-6f;
        const float rden  = 1.f / denom;

        float4 ht;
        ht.x = nt.x * rden; ht.y = nt.y * rden;
        ht.z = nt.z * rden; ht.w = nt.w * rden;

        // LayerNorm over 256 values (64 lanes x 4)
        float s = ht.x + ht.y + ht.z + ht.w;
#pragma unroll
        for (int o = 32; o > 0; o >>= 1) s += __shfl_down(s, o, 64);
        s = __shfl(s, 0, 64);
        const float mu = s * (1.f / 256.f);

        float vs = (ht.x - mu) * (ht.x - mu) + (ht.y - mu) * (ht.y - mu)
                 + (ht.z - mu) * (ht.z - mu) + (ht.w - mu) * (ht.w - mu);
#pragma unroll
        for (int o = 32; o > 0; o >>= 1) vs += __shfl_down(vs, o, 64);
        vs = __shfl(vs, 0, 64);
        const float rs = rsqrtf(vs * (1.f / 256.f) + 1e-6f);

        const float4 lns = ((const float4*)(ln_s + h * HDd))[t];
        float4 hn;
        hn.x = (ht.x - mu) * rs * lns.x;
        hn.y = (ht.y - mu) * rs * lns.y;
        hn.z = (ht.z - mu) * rs * lns.z;
        hn.w = (ht.w - mu) * rs * lns.w;
        ((float4*)(out + H_OFF + (size_t)b * Hh + h * HDd))[t] = hn;
    }
}

extern "C" void kernel_launch(void* const* d_in, const int* in_sizes, int n_in,
                              void* d_out, int out_size, void* d_ws, size_t ws_size,
                              hipStream_t stream)
{
    const float* q    = (const float*)d_in[0];
    const float* k    = (const float*)d_in[1];
    const float* v    = (const float*)d_in[2];
    const float* c    = (const float*)d_in[3];
    const float* n    = (const float*)d_in[4];
    const float* m    = (const float*)d_in[5];
    const float* wi_k = (const float*)d_in[6];
    const float* wi_b = (const float*)d_in[7];
    const float* wf_k = (const float*)d_in[8];
    const float* wf_b = (const float*)d_in[9];
    const float* ln_s = (const float*)d_in[10];
    float* out = (float*)d_out;

    fused_cell_kernel<<<dim3(Bb * NHh), dim3(1024), 0, stream>>>(
        q, k, v, c, n, m, wi_k, wi_b, wf_k, wf_b, ln_s, out);
}

// Round 4
// 262.201 us; speedup vs baseline: 1.0362x; 1.0267x over previous
//
#include <hip/hip_runtime.h>
#include <math.h>

typedef float f32x4 __attribute__((ext_vector_type(4)));

// Problem constants: B=64, H=2048, NH=8, HD=256
constexpr int Bb  = 64;
constexpr int Hh  = 2048;
constexpr int NHh = 8;
constexpr int HDd = 256;

// Output flat offsets (c_new, n_new, m_new, h_norm), all f32
constexpr size_t C_OFF = 0;
constexpr size_t N_OFF = (size_t)Bb * NHh * HDd * HDd;            // 33554432
constexpr size_t M_OFF = N_OFF + (size_t)Bb * NHh * HDd;          // 33685504
constexpr size_t H_OFF = M_OFF + (size_t)Bb * NHh;                // 33686016

// ---------------------------------------------------------------------------
// Kernel A (64 blocks x 256): gates + n_new + denominator, and zeroes the
// h_norm region (reused as the atomic nom accumulator for kernel B).
// ws per (b,h): [4*blk +0]=f', +1=i', +2=m_new, +3=denom
// ---------------------------------------------------------------------------
__global__ __launch_bounds__(256) void gates_kernel(
    const float* __restrict__ q, const float* __restrict__ k,
    const float* __restrict__ v, const float* __restrict__ n_in,
    const float* __restrict__ m_in,
    const float* __restrict__ wi_k, const float* __restrict__ wi_b,
    const float* __restrict__ wf_k, const float* __restrict__ wf_b,
    float* __restrict__ ws, float* __restrict__ out)
{
    const int b    = blockIdx.x;
    const int t    = threadIdx.x;
    const int lane = t & 63;
    const int wv   = t >> 6;

    // zero nom accumulator region for this batch (2048 floats, 8 per thread)
    {
        f32x4 z = {0.f, 0.f, 0.f, 0.f};
        f32x4* zp = (f32x4*)(out + H_OFF + (size_t)b * Hh) + t * 2;
        zp[0] = z; zp[1] = z;
    }

    float ai[8], af[8];
#pragma unroll
    for (int i = 0; i < 8; ++i) { ai[i] = 0.f; af[i] = 0.f; }

#pragma unroll 4
    for (int j = 0; j < 24; ++j) {
        const int r = t + 256 * j;
        float x;
        if (r < Hh)            x = q[b * Hh + r];
        else if (r < 2 * Hh)   x = k[b * Hh + r - Hh];
        else                   x = v[b * Hh + r - 2 * Hh];

        const f32x4 wa = *(const f32x4*)(wi_k + (size_t)r * 8);
        const f32x4 wb = *(const f32x4*)(wi_k + (size_t)r * 8 + 4);
        ai[0] = fmaf(x, wa[0], ai[0]); ai[1] = fmaf(x, wa[1], ai[1]);
        ai[2] = fmaf(x, wa[2], ai[2]); ai[3] = fmaf(x, wa[3], ai[3]);
        ai[4] = fmaf(x, wb[0], ai[4]); ai[5] = fmaf(x, wb[1], ai[5]);
        ai[6] = fmaf(x, wb[2], ai[6]); ai[7] = fmaf(x, wb[3], ai[7]);

        const f32x4 fa = *(const f32x4*)(wf_k + (size_t)r * 8);
        const f32x4 fb = *(const f32x4*)(wf_k + (size_t)r * 8 + 4);
        af[0] = fmaf(x, fa[0], af[0]); af[1] = fmaf(x, fa[1], af[1]);
        af[2] = fmaf(x, fa[2], af[2]); af[3] = fmaf(x, fa[3], af[3]);
        af[4] = fmaf(x, fb[0], af[4]); af[5] = fmaf(x, fb[1], af[5]);
        af[6] = fmaf(x, fb[2], af[6]); af[7] = fmaf(x, fb[3], af[7]);
    }

#pragma unroll
    for (int i = 0; i < 8; ++i) {
#pragma unroll
        for (int o = 32; o > 0; o >>= 1) {
            ai[i] += __shfl_down(ai[i], o, 64);
            af[i] += __shfl_down(af[i], o, 64);
        }
    }

    __shared__ float s_part[4][16];
    __shared__ float s_g[8][3];     // f', i', m_new per head
    if (lane == 0) {
#pragma unroll
        for (int i = 0; i < 8; ++i) {
            s_part[wv][i]     = ai[i];
            s_part[wv][8 + i] = af[i];
        }
    }
    __syncthreads();

    if (t < 8) {
        const int h = t;
        const float it = s_part[0][h] + s_part[1][h] + s_part[2][h] + s_part[3][h]
                         + wi_b[h];
        const float ft = s_part[0][8 + h] + s_part[1][8 + h] + s_part[2][8 + h]
                         + s_part[3][8 + h] + wf_b[h];
        const float logf_ = -(fmaxf(-ft, 0.f) + log1pf(expf(-fabsf(ft))));
        const float m_old = m_in[b * NHh + h];
        const float m_new = fmaxf(logf_ + m_old, it);
        const float fp    = expf(logf_ + m_old - m_new);
        const float ip    = expf(it - m_new);
        const int blk = b * NHh + h;
        s_g[h][0] = fp; s_g[h][1] = ip; s_g[h][2] = m_new;
        ws[blk * 4 + 0] = fp;
        ws[blk * 4 + 1] = ip;
        ws[blk * 4 + 2] = m_new;
        out[M_OFF + blk] = m_new;
    }
    __syncthreads();

    // n_new (8 heads x 256) + per-head denominator dot
    float pd[8];
#pragma unroll
    for (int h = 0; h < 8; ++h) {
        const float kv = k[b * Hh + h * HDd + t] * 0.0625f;   // 1/sqrt(256)
        const float nn = fmaf(s_g[h][0], n_in[((size_t)b * 8 + h) * HDd + t],
                              s_g[h][1] * kv);
        out[N_OFF + ((size_t)b * 8 + h) * HDd + t] = nn;
        pd[h] = q[b * Hh + h * HDd + t] * nn;
    }
#pragma unroll
    for (int h = 0; h < 8; ++h)
#pragma unroll
        for (int o = 32; o > 0; o >>= 1) pd[h] += __shfl_down(pd[h], o, 64);

    __shared__ float s_dp[4][8];
    if (lane == 0) {
#pragma unroll
        for (int h = 0; h < 8; ++h) s_dp[wv][h] = pd[h];
    }
    __syncthreads();
    if (t < 8) {
        const float dd = s_dp[0][t] + s_dp[1][t] + s_dp[2][t] + s_dp[3][t];
        ws[(b * 8 + t) * 4 + 3] = fmaxf(fabsf(dd), expf(-s_g[t][2])) + 1e-6f;
    }
}

// ---------------------------------------------------------------------------
// Kernel B (4096 blocks x 256): copy-shaped c-stream. Block = 32-row stripe
// of one (b,h) tile. Wave wv owns 8 consecutive rows; lane owns float4-col.
// 8 fully-unrolled nontemporal load/store pairs per thread; qh^T c_new
// partials atomicAdd'ed into out[H_OFF + tile*256 + ...] (pre-zeroed by A).
// ---------------------------------------------------------------------------
__global__ __launch_bounds__(256) void stream_kernel(
    const float* __restrict__ q, const float* __restrict__ k,
    const float* __restrict__ v, const float* __restrict__ c_in,
    const float* __restrict__ ws, float* __restrict__ out)
{
    const int blk  = blockIdx.x;
    const int tile = blk >> 3;      // b*8 + h
    const int s    = blk & 7;       // stripe
    const int b    = tile >> 3;
    const int h    = tile & 7;
    const int t    = threadIdx.x;
    const int lane = t & 63;
    const int wv   = t >> 6;

    __shared__ float s_kh[32];
    __shared__ float s_qh[32];
    __shared__ f32x4 s_nom[4][64];

    if (t < 32) {
        const int r = s * 32 + t;
        s_kh[t] = k[b * Hh + h * HDd + r] * 0.0625f;
        s_qh[t] = q[b * Hh + h * HDd + r];
    }
    const float fp  = ws[tile * 4 + 0];
    const float ip  = ws[tile * 4 + 1];
    const f32x4 vh4 = ((const f32x4*)(v + b * Hh + h * HDd))[lane];
    __syncthreads();

    const size_t cbase = (size_t)tile * (HDd * HDd);
    const f32x4* cin   = (const f32x4*)(c_in + cbase);
    f32x4*       cout  = (f32x4*)(out + C_OFF + cbase);
    f32x4 nom = {0.f, 0.f, 0.f, 0.f};
    const int rb = wv * 8;

#pragma unroll
    for (int j = 0; j < 8; ++j) {
        const int   r   = rb + j;                 // row within stripe
        const float a   = ip * s_kh[r];
        const float qh1 = s_qh[r];
        const int   idx = (s * 32 + r) * 64 + lane;
        f32x4 cv = __builtin_nontemporal_load(cin + idx);
        f32x4 cn = fp * cv + a * vh4;
        __builtin_nontemporal_store(cn, cout + idx);
        nom += qh1 * cn;
    }
    s_nom[wv][lane] = nom;
    __syncthreads();

    if (t < 64) {
        f32x4 sum = s_nom[0][t] + s_nom[1][t] + s_nom[2][t] + s_nom[3][t];
        float* dst = out + H_OFF + (size_t)tile * HDd + t * 4;
        atomicAdd(dst + 0, sum[0]);
        atomicAdd(dst + 1, sum[1]);
        atomicAdd(dst + 2, sum[2]);
        atomicAdd(dst + 3, sum[3]);
    }
}

// ---------------------------------------------------------------------------
// Kernel C (512 blocks x 64): finish h_tilde -> LayerNorm, in place.
// ---------------------------------------------------------------------------
__global__ __launch_bounds__(64) void ln_kernel(
    const float* __restrict__ ln_s, const float* __restrict__ ws,
    float* __restrict__ out)
{
    const int blk  = blockIdx.x;    // b*8 + h
    const int h    = blk & 7;
    const int lane = threadIdx.x;

    float* hp = out + H_OFF + (size_t)blk * HDd;
    const f32x4 nt   = ((const f32x4*)hp)[lane];
    const float rden = 1.f / ws[blk * 4 + 3];
    f32x4 ht = nt * rden;

    float s = ht[0] + ht[1] + ht[2] + ht[3];
#pragma unroll
    for (int o = 32; o > 0; o >>= 1) s += __shfl_down(s, o, 64);
    s = __shfl(s, 0, 64);
    const float mu = s * (1.f / 256.f);

    const f32x4 d = ht - mu;
    float vs = d[0] * d[0] + d[1] * d[1] + d[2] * d[2] + d[3] * d[3];
#pragma unroll
    for (int o = 32; o > 0; o >>= 1) vs += __shfl_down(vs, o, 64);
    vs = __shfl(vs, 0, 64);
    const float rs = rsqrtf(vs * (1.f / 256.f) + 1e-6f);

    const f32x4 lns = ((const f32x4*)(ln_s + h * HDd))[lane];
    ((f32x4*)hp)[lane] = d * rs * lns;
}

extern "C" void kernel_launch(void* const* d_in, const int* in_sizes, int n_in,
                              void* d_out, int out_size, void* d_ws, size_t ws_size,
                              hipStream_t stream)
{
    const float* q    = (const float*)d_in[0];
    const float* k    = (const float*)d_in[1];
    const float* v    = (const float*)d_in[2];
    const float* c    = (const float*)d_in[3];
    const float* n    = (const float*)d_in[4];
    const float* m    = (const float*)d_in[5];
    const float* wi_k = (const float*)d_in[6];
    const float* wi_b = (const float*)d_in[7];
    const float* wf_k = (const float*)d_in[8];
    const float* wf_b = (const float*)d_in[9];
    const float* ln_s = (const float*)d_in[10];
    float* out = (float*)d_out;
    float* ws  = (float*)d_ws;

    gates_kernel<<<dim3(Bb), dim3(256), 0, stream>>>(
        q, k, v, n, m, wi_k, wi_b, wf_k, wf_b, ws, out);
    stream_kernel<<<dim3(Bb * NHh * 8), dim3(256), 0, stream>>>(
        q, k, v, c, ws, out);
    ln_kernel<<<dim3(Bb * NHh), dim3(64), 0, stream>>>(ln_s, ws, out);
}